// Round 15
// baseline (436.221 us; speedup 1.0000x reference)
//
#include <hip/hip_runtime.h>

#define Bc 16
#define Cc 512
#define Tc 2048
#define QT 128
#define KT 64
#define NT 32     // Tc / KT
#define LTS 66    // kqv LDS transposed-tile row stride (ushort), 64+2 pad

typedef __attribute__((ext_vector_type(8)))  short short8;
typedef __attribute__((ext_vector_type(4)))  float f32x4;
typedef __attribute__((ext_vector_type(16))) float f32x16;
typedef unsigned short u16;

static __device__ __forceinline__ u16 f2bf(float x) {
  unsigned u = __float_as_uint(x);
  u += 0x7FFF + ((u >> 16) & 1);   // RNE
  return (u16)(u >> 16);
}

// Pack 2 f32 -> 2 bf16 in one VALU op (no builtin on gfx950).
static __device__ __forceinline__ unsigned cvt_pk_bf16(float lo, float hi) {
  unsigned r;
  asm("v_cvt_pk_bf16_f32 %0, %1, %2" : "=v"(r) : "v"(lo), "v"(hi));
  return r;
}

// Barrier that waits ONLY on LDS ops (lgkmcnt) — outstanding global loads
// stay in flight across it.
static __device__ __forceinline__ void block_sync_lds() {
  __builtin_amdgcn_sched_barrier(0);
  asm volatile("s_waitcnt lgkmcnt(0)" ::: "memory");
  __builtin_amdgcn_s_barrier();
  __builtin_amdgcn_sched_barrier(0);
}

// ---------------- Kernel 0: W -> bf16 (fused k||q), bias -> bkq ----------------
__global__ __launch_bounds__(256) void prep_kernel(
    const float* __restrict__ Wk, const float* __restrict__ Wq,
    const float* __restrict__ bk, const float* __restrict__ bq,
    u16* __restrict__ Wbf, float* __restrict__ bkq)
{
  int idx  = blockIdx.x * 256 + threadIdx.x;
  int base = idx * 4;
  if (base < 128 * Cc) {
    int ch = base >> 9;
    int c  = base & (Cc - 1);
    const float* src = (ch < 64) ? (Wk + (size_t)ch * Cc + c)
                                 : (Wq + (size_t)(ch - 64) * Cc + c);
    f32x4 w = *reinterpret_cast<const f32x4*>(src);
    uint2 o;
    o.x = (unsigned)f2bf(w[0]) | ((unsigned)f2bf(w[1]) << 16);
    o.y = (unsigned)f2bf(w[2]) | ((unsigned)f2bf(w[3]) << 16);
    *reinterpret_cast<uint2*>(Wbf + base) = o;
  }
  if (idx < 128) bkq[idx] = (idx < 64) ? bk[idx] : bq[idx - 64];
}

// ---------------- Kernel 1: kq[t][ch] via MFMA + vbf16 emission ----------------
__global__ __launch_bounds__(256) void kqv_kernel(
    const float* __restrict__ v, const u16* __restrict__ Wbf,
    const float* __restrict__ bkq, u16* __restrict__ kq, u16* __restrict__ vbf)
{
  __shared__ u16 LDSt[2][64][LTS];
  const int b   = blockIdx.y;
  const int t0  = blockIdx.x * 64;
  const int tid = threadIdx.x;
  const int lane = tid & 63;
  const int w    = tid >> 6;
  const int l15  = lane & 15;
  const int lg   = lane >> 4;

  f32x4 acc[8];
  #pragma unroll
  for (int mt = 0; mt < 8; ++mt) acc[mt] = f32x4{0.f, 0.f, 0.f, 0.f};

  const float* vb = v + (size_t)b * Cc * Tc + t0;
  float x[16];
  #pragma unroll
  for (int r = 0; r < 16; ++r) x[r] = vb[(size_t)(w * 16 + r) * Tc + lane];

  int buf = 0;
  for (int c0 = 0; c0 < Cc; c0 += 64, buf ^= 1) {
    #pragma unroll
    for (int r = 0; r < 16; ++r) {
      u16 hb = f2bf(x[r]);
      LDSt[buf][lane][w * 16 + r] = hb;
      vbf[((size_t)b * Cc + c0 + w * 16 + r) * Tc + t0 + lane] = hb;
    }
    block_sync_lds();
    if (c0 + 64 < Cc) {
      #pragma unroll
      for (int r = 0; r < 16; ++r)
        x[r] = vb[(size_t)(c0 + 64 + w * 16 + r) * Tc + lane];
    }
    #pragma unroll
    for (int ks = 0; ks < 2; ++ks) {
      short8 bfrag = *reinterpret_cast<const short8*>(&LDSt[buf][w * 16 + l15][ks * 32 + lg * 8]);
      #pragma unroll
      for (int mt = 0; mt < 8; ++mt) {
        short8 afrag = *reinterpret_cast<const short8*>(
            Wbf + (size_t)(mt * 16 + l15) * Cc + c0 + ks * 32 + lg * 8);
        acc[mt] = __builtin_amdgcn_mfma_f32_16x16x32_bf16(afrag, bfrag, acc[mt], 0, 0, 0);
      }
    }
  }
  const int t = t0 + w * 16 + l15;
  u16* op = kq + ((size_t)b * Tc + t) * 128;
  #pragma unroll
  for (int mt = 0; mt < 8; ++mt) {
    int chb = mt * 16 + lg * 4;
    uint2 o;
    o.x = cvt_pk_bf16(acc[mt][0] + bkq[chb + 0], acc[mt][1] + bkq[chb + 1]);
    o.y = cvt_pk_bf16(acc[mt][2] + bkq[chb + 2], acc[mt][3] + bkq[chb + 3]);
    *reinterpret_cast<uint2*>(op + chb) = o;
  }
}

// ---------------- Kernel 2: producer-consumer wave-specialized flash attention ----------------
// 8 waves, two role groups paired on SIMDs (wid and wid+4 share a SIMD):
//   group A (wid<4): j 0..63   |  group B (wid>=4): j 64..127
// Each slot, one group does S+exp+P-write (VALU) while the other does PV (MFMA),
// then they swap -> each SIMD always has one MFMA-heavy + one VALU-heavy wave.
// P per group [2 buf][64 j][64 i] bf16, XOR-swizzled (r14-verified layout).
// PV via mfma_f32_32x32x16 (r14-verified operand mapping).
__global__ __launch_bounds__(512, 2) void attn_kernel(
    const float* __restrict__ v, const u16* __restrict__ vbf,
    const u16* __restrict__ kq, const float* __restrict__ gamma_p,
    float* __restrict__ out)
{
  __shared__ u16 P[2][2][64 * 64];     // [grp][buf], 32 KB total, swizzled
  __shared__ __align__(16) float ep_lds[8][32 * 36];
  __shared__ float lsum_lds[QT];
  __shared__ __align__(16) float linv_lds[QT];

  // XCD-aware swizzle: 256 blocks, 8 XCDs -> each XCD sees 2 consecutive b's
  const int L   = blockIdx.x;
  const int lin = (L & 7) * 32 + (L >> 3);
  const int b   = lin >> 4;
  const int j0  = (lin & 15) * QT;
  const int tid = threadIdx.x;
  const int lane = tid & 63;
  const int wid  = tid >> 6;      // 0..7
  const int l15  = lane & 15;
  const int lg   = lane >> 4;     // 0..3
  const int l31  = lane & 31;
  const int kh   = lane >> 5;     // 0..1
  const int grp  = wid >> 2;      // 0 = A, 1 = B
  const int wg   = wid & 3;       // wave within group
  const int c0   = wg * 128;      // PV channel slice (4 waves x 128 = 512)
  const int sj   = grp * 64 + wg * 16;   // S j-slice (block-local)
  const int prow_base = (wg * 16 + l15) * 64;  // P write row base (group-local)

  // Q B-fragments for S (16x16): n=j=l15, k=d=lg*8+e
  short8 qf0, qf1;
  {
    const u16* qp = kq + (size_t)(b * Tc + j0 + sj + l15) * 128 + 64 + lg * 8;
    qf0 = *reinterpret_cast<const short8*>(qp);
    qf1 = *reinterpret_cast<const short8*>(qp + 32);
  }

  f32x16 O32[4][2];   // [ct][jt]: col j = grp*64 + jt*32 + l31; row c via reg map
  #pragma unroll
  for (int a = 0; a < 4; ++a)
    #pragma unroll
    for (int bb = 0; bb < 2; ++bb)
      #pragma unroll
      for (int e = 0; e < 16; ++e) O32[a][bb][e] = 0.f;

  float lsum = 0.f;

  const u16* kbase = kq + (size_t)b * Tc * 128 + lg * 8;
  const u16* vbase = vbf + ((size_t)b * Cc + c0) * Tc;

  short8 kf[4][2];       // K frags for next S tile (per-wave copy)
  short8 vf01[4][2];     // V A-frags ks 0..1, prefetched cross-slot

  // ---- prologue: kf <- K(0), vf01 <- V(0); S(0) -> P[grp][0]; kf <- K(1) ----
  #pragma unroll
  for (int it = 0; it < 4; ++it) {
    const u16* kp = kbase + (size_t)(it * 16 + l15) * 128;
    kf[it][0] = *reinterpret_cast<const short8*>(kp);
    kf[it][1] = *reinterpret_cast<const short8*>(kp + 32);
  }
  #pragma unroll
  for (int ct = 0; ct < 4; ++ct)
    #pragma unroll
    for (int kk = 0; kk < 2; ++kk)
      vf01[ct][kk] = *reinterpret_cast<const short8*>(
          vbase + (size_t)(ct * 32 + l31) * Tc + kk * 16 + kh * 8);
  {
    f32x4 sacc[4];
    #pragma unroll
    for (int it = 0; it < 4; ++it) {
      f32x4 s = f32x4{0.f, 0.f, 0.f, 0.f};
      s = __builtin_amdgcn_mfma_f32_16x16x32_bf16(kf[it][0], qf0, s, 0, 0, 0);
      s = __builtin_amdgcn_mfma_f32_16x16x32_bf16(kf[it][1], qf1, s, 0, 0, 0);
      sacc[it] = s;
    }
    u16* prow = &P[grp][0][prow_base];
    #pragma unroll
    for (int it = 0; it < 4; ++it) {
      float p0 = __expf(sacc[it][0]);
      float p1 = __expf(sacc[it][1]);
      float p2 = __expf(sacc[it][2]);
      float p3 = __expf(sacc[it][3]);
      lsum += (p0 + p1) + (p2 + p3);
      uint2 wv;
      wv.x = cvt_pk_bf16(p0, p1);
      wv.y = cvt_pk_bf16(p2, p3);
      int chk = ((it * 2 + (lg >> 1)) ^ (l15 & 7)) * 8 + (lg & 1) * 4;
      *reinterpret_cast<uint2*>(prow + chk) = wv;
    }
  }
  #pragma unroll
  for (int it = 0; it < 4; ++it) {
    const u16* kp = kbase + (size_t)(KT + it * 16 + l15) * 128;
    kf[it][0] = *reinterpret_cast<const short8*>(kp);
    kf[it][1] = *reinterpret_cast<const short8*>(kp + 32);
  }
  block_sync_lds();

  for (int i = 0; i < NT; ++i) {
    const int i0 = i * KT;
    const int buf = i & 1;

    #pragma unroll
    for (int slot = 0; slot < 2; ++slot) {
      // role: slot0 -> A produces / B consumes; slot1 -> swapped
      const bool produce = (slot == 0) ? (grp == 0) : (grp == 1);

      if (produce) {
        // ---- S(i+1) + exp + publish P[grp][buf^1] ----
        if (i + 1 < NT) {
          f32x4 sacc[4];
          #pragma unroll
          for (int it = 0; it < 4; ++it) {
            f32x4 s = f32x4{0.f, 0.f, 0.f, 0.f};
            s = __builtin_amdgcn_mfma_f32_16x16x32_bf16(kf[it][0], qf0, s, 0, 0, 0);
            s = __builtin_amdgcn_mfma_f32_16x16x32_bf16(kf[it][1], qf1, s, 0, 0, 0);
            sacc[it] = s;
          }
          // issue kf <- K(i+2)
          if (i + 2 < NT) {
            #pragma unroll
            for (int it = 0; it < 4; ++it) {
              const u16* kp = kbase + (size_t)((i0 + 2 * KT) + it * 16 + l15) * 128;
              kf[it][0] = *reinterpret_cast<const short8*>(kp);
              kf[it][1] = *reinterpret_cast<const short8*>(kp + 32);
            }
          }
          u16* prow = &P[grp][buf ^ 1][prow_base];
          #pragma unroll
          for (int it = 0; it < 4; ++it) {
            float p0 = __expf(sacc[it][0]);
            float p1 = __expf(sacc[it][1]);
            float p2 = __expf(sacc[it][2]);
            float p3 = __expf(sacc[it][3]);
            lsum += (p0 + p1) + (p2 + p3);
            uint2 wv;
            wv.x = cvt_pk_bf16(p0, p1);
            wv.y = cvt_pk_bf16(p2, p3);
            int chk = ((it * 2 + (lg >> 1)) ^ (l15 & 7)) * 8 + (lg & 1) * 4;
            *reinterpret_cast<uint2*>(prow + chk) = wv;
          }
        }
      } else {
        // ---- PV(i): O[c][j] += V[c,i] P[i,j] via 32x32x16 ----
        short8 vf23[4][2];
        #pragma unroll
        for (int ct = 0; ct < 4; ++ct)
          #pragma unroll
          for (int kk = 0; kk < 2; ++kk)
            vf23[ct][kk] = *reinterpret_cast<const short8*>(
                vbase + (size_t)(ct * 32 + l31) * Tc + i0 + 32 + kk * 16 + kh * 8);

        __builtin_amdgcn_s_setprio(1);
        #pragma unroll
        for (int ks = 0; ks < 4; ++ks) {
          short8 pf[2];
          #pragma unroll
          for (int jt = 0; jt < 2; ++jt) {
            int row = jt * 32 + l31;
            int chk = ((ks * 2 + kh) ^ (row & 7)) * 8;
            pf[jt] = *reinterpret_cast<const short8*>(&P[grp][buf][row * 64 + chk]);
          }
          #pragma unroll
          for (int ct = 0; ct < 4; ++ct) {
            const short8 vsel = (ks < 2) ? vf01[ct][ks] : vf23[ct][ks - 2];
            #pragma unroll
            for (int jt = 0; jt < 2; ++jt)
              O32[ct][jt] = __builtin_amdgcn_mfma_f32_32x32x16_bf16(vsel, pf[jt], O32[ct][jt], 0, 0, 0);
          }
        }
        __builtin_amdgcn_s_setprio(0);

        // issue vf01 <- V(i+1)
        if (i + 1 < NT) {
          #pragma unroll
          for (int ct = 0; ct < 4; ++ct)
            #pragma unroll
            for (int kk = 0; kk < 2; ++kk)
              vf01[ct][kk] = *reinterpret_cast<const short8*>(
                  vbase + (size_t)(ct * 32 + l31) * Tc + (i0 + KT) + kk * 16 + kh * 8);
        }
      }
      block_sync_lds();
    }
  }

  // ---- denominators ----
  lsum += __shfl_xor(lsum, 16);
  lsum += __shfl_xor(lsum, 32);
  if (lane < 16) lsum_lds[sj + lane] = lsum;
  __syncthreads();
  const float gamma = *gamma_p;
  if (tid < QT) linv_lds[tid] = gamma / lsum_lds[tid];
  __syncthreads();

  // ---- epilogue: per-wave LDS transpose of each 32x32 tile, float4 I/O ----
  float* ep = ep_lds[wid];
  const int rd_row = lane >> 3;   // 0..7 (+8h)
  const int rd_ch  = lane & 7;    // j quad
  #pragma unroll
  for (int ct = 0; ct < 4; ++ct) {
    #pragma unroll
    for (int jt = 0; jt < 2; ++jt) {
      #pragma unroll
      for (int reg = 0; reg < 16; ++reg) {
        int cl = (reg & 3) + 8 * (reg >> 2) + 4 * kh;
        ep[cl * 36 + l31] = O32[ct][jt][reg];
      }
      asm volatile("s_waitcnt lgkmcnt(0)" ::: "memory");
      __builtin_amdgcn_sched_barrier(0);
      #pragma unroll
      for (int h = 0; h < 4; ++h) {
        const int row = rd_row + 8 * h;
        f32x4 o4 = *reinterpret_cast<const f32x4*>(&ep[row * 36 + rd_ch * 4]);
        const int jg = grp * 64 + jt * 32 + rd_ch * 4;
        f32x4 li = *reinterpret_cast<const f32x4*>(&linv_lds[jg]);
        const int c_glob = c0 + ct * 32 + row;
        const float* vr = v + ((size_t)(b * Cc + c_glob)) * Tc + j0 + jg;
        float* orow = out + ((size_t)(b * Cc + c_glob)) * Tc + j0 + jg;
        f32x4 v4 = *reinterpret_cast<const f32x4*>(vr);
        f32x4 o;
        o[0] = v4[0] + li[0] * o4[0];
        o[1] = v4[1] + li[1] * o4[1];
        o[2] = v4[2] + li[2] * o4[2];
        o[3] = v4[3] + li[3] * o4[3];
        *reinterpret_cast<f32x4*>(orow) = o;
      }
      asm volatile("s_waitcnt lgkmcnt(0)" ::: "memory");
      __builtin_amdgcn_sched_barrier(0);
    }
  }
}

extern "C" void kernel_launch(void* const* d_in, const int* in_sizes, int n_in,
                              void* d_out, int out_size, void* d_ws, size_t ws_size,
                              hipStream_t stream) {
  const float* v  = (const float*)d_in[0];
  const float* Wk = (const float*)d_in[1];
  const float* bk = (const float*)d_in[2];
  const float* Wq = (const float*)d_in[3];
  const float* bq = (const float*)d_in[4];
  const float* gm = (const float*)d_in[5];
  float* out = (float*)d_out;

  char* ws = (char*)d_ws;
  u16*   kqb = (u16*)ws;                                   //  8,388,608 B
  u16*   vbf = (u16*)(ws + 8388608);                       // 33,554,432 B
  u16*   Wbf = (u16*)(ws + 8388608 + 33554432);            //    131,072 B
  float* bkq = (float*)(ws + 8388608 + 33554432 + 131072); //        512 B

  prep_kernel<<<dim3(64), dim3(256), 0, stream>>>(Wk, Wq, bk, bq, Wbf, bkq);
  kqv_kernel<<<dim3(Tc / 64, Bc), dim3(256), 0, stream>>>(v, Wbf, bkq, kqb, vbf);
  attn_kernel<<<dim3((Tc / QT) * Bc), dim3(512), 0, stream>>>(v, vbf, kqb, gm, out);
}

// Round 16
// 240.768 us; speedup vs baseline: 1.8118x; 1.8118x over previous
//
#include <hip/hip_runtime.h>

#define Bc 16
#define Cc 512
#define Tc 2048
#define QTJ 64    // j per attn block
#define KT 64
#define NT 32     // Tc / KT
#define LTS 66    // kqv LDS transposed-tile row stride (ushort), 64+2 pad

typedef __attribute__((ext_vector_type(8)))  short short8;
typedef __attribute__((ext_vector_type(4)))  float f32x4;
typedef __attribute__((ext_vector_type(16))) float f32x16;
typedef unsigned short u16;

static __device__ __forceinline__ u16 f2bf(float x) {
  unsigned u = __float_as_uint(x);
  u += 0x7FFF + ((u >> 16) & 1);   // RNE
  return (u16)(u >> 16);
}

// Pack 2 f32 -> 2 bf16 in one VALU op (no builtin on gfx950).
static __device__ __forceinline__ unsigned cvt_pk_bf16(float lo, float hi) {
  unsigned r;
  asm("v_cvt_pk_bf16_f32 %0, %1, %2" : "=v"(r) : "v"(lo), "v"(hi));
  return r;
}

// Barrier that waits ONLY on LDS ops (lgkmcnt) — outstanding global loads
// stay in flight across it.
static __device__ __forceinline__ void block_sync_lds() {
  __builtin_amdgcn_sched_barrier(0);
  asm volatile("s_waitcnt lgkmcnt(0)" ::: "memory");
  __builtin_amdgcn_s_barrier();
  __builtin_amdgcn_sched_barrier(0);
}

// ---------------- Kernel 0: W -> bf16 (fused k||q), bias -> bkq ----------------
__global__ __launch_bounds__(256) void prep_kernel(
    const float* __restrict__ Wk, const float* __restrict__ Wq,
    const float* __restrict__ bk, const float* __restrict__ bq,
    u16* __restrict__ Wbf, float* __restrict__ bkq)
{
  int idx  = blockIdx.x * 256 + threadIdx.x;
  int base = idx * 4;
  if (base < 128 * Cc) {
    int ch = base >> 9;
    int c  = base & (Cc - 1);
    const float* src = (ch < 64) ? (Wk + (size_t)ch * Cc + c)
                                 : (Wq + (size_t)(ch - 64) * Cc + c);
    f32x4 w = *reinterpret_cast<const f32x4*>(src);
    uint2 o;
    o.x = (unsigned)f2bf(w[0]) | ((unsigned)f2bf(w[1]) << 16);
    o.y = (unsigned)f2bf(w[2]) | ((unsigned)f2bf(w[3]) << 16);
    *reinterpret_cast<uint2*>(Wbf + base) = o;
  }
  if (idx < 128) bkq[idx] = (idx < 64) ? bk[idx] : bq[idx - 64];
}

// ---------------- Kernel 1: kq[t][ch] via MFMA + vbf16 emission ----------------
__global__ __launch_bounds__(256) void kqv_kernel(
    const float* __restrict__ v, const u16* __restrict__ Wbf,
    const float* __restrict__ bkq, u16* __restrict__ kq, u16* __restrict__ vbf)
{
  __shared__ u16 LDSt[2][64][LTS];
  const int b   = blockIdx.y;
  const int t0  = blockIdx.x * 64;
  const int tid = threadIdx.x;
  const int lane = tid & 63;
  const int w    = tid >> 6;
  const int l15  = lane & 15;
  const int lg   = lane >> 4;

  f32x4 acc[8];
  #pragma unroll
  for (int mt = 0; mt < 8; ++mt) acc[mt] = f32x4{0.f, 0.f, 0.f, 0.f};

  const float* vb = v + (size_t)b * Cc * Tc + t0;
  float x[16];
  #pragma unroll
  for (int r = 0; r < 16; ++r) x[r] = vb[(size_t)(w * 16 + r) * Tc + lane];

  int buf = 0;
  for (int c0 = 0; c0 < Cc; c0 += 64, buf ^= 1) {
    #pragma unroll
    for (int r = 0; r < 16; ++r) {
      u16 hb = f2bf(x[r]);
      LDSt[buf][lane][w * 16 + r] = hb;
      vbf[((size_t)b * Cc + c0 + w * 16 + r) * Tc + t0 + lane] = hb;
    }
    block_sync_lds();
    if (c0 + 64 < Cc) {
      #pragma unroll
      for (int r = 0; r < 16; ++r)
        x[r] = vb[(size_t)(c0 + 64 + w * 16 + r) * Tc + lane];
    }
    #pragma unroll
    for (int ks = 0; ks < 2; ++ks) {
      short8 bfrag = *reinterpret_cast<const short8*>(&LDSt[buf][w * 16 + l15][ks * 32 + lg * 8]);
      #pragma unroll
      for (int mt = 0; mt < 8; ++mt) {
        short8 afrag = *reinterpret_cast<const short8*>(
            Wbf + (size_t)(mt * 16 + l15) * Cc + c0 + ks * 32 + lg * 8);
        acc[mt] = __builtin_amdgcn_mfma_f32_16x16x32_bf16(afrag, bfrag, acc[mt], 0, 0, 0);
      }
    }
  }
  const int t = t0 + w * 16 + l15;
  u16* op = kq + ((size_t)b * Tc + t) * 128;
  #pragma unroll
  for (int mt = 0; mt < 8; ++mt) {
    int chb = mt * 16 + lg * 4;
    uint2 o;
    o.x = cvt_pk_bf16(acc[mt][0] + bkq[chb + 0], acc[mt][1] + bkq[chb + 1]);
    o.y = cvt_pk_bf16(acc[mt][2] + bkq[chb + 2], acc[mt][3] + bkq[chb + 3]);
    *reinterpret_cast<uint2*>(op + chb) = o;
  }
}

// ---------------- Kernel 2: decorrelated 4-wave blocks, 2 blocks/CU ----------------
// QTJ=64, 4 waves/block: wave wid owns S j-tile wid*16 and PV channel slice
// wid*128. 512 blocks -> 2 independent blocks/CU: the 2 waves per SIMD come
// from DIFFERENT blocks and drift freely (PV of one covers S/exp of the other).
// r14's verified pieces: rotated pipeline, K-prefetch, swizzled P, 32x32 PV.
__global__ __launch_bounds__(256, 2) void attn_kernel(
    const float* __restrict__ v, const u16* __restrict__ vbf,
    const u16* __restrict__ kq, const float* __restrict__ gamma_p,
    float* __restrict__ out)
{
  __shared__ u16 P[2][64 * 64];        // [buf][j][i] swizzled, 16 KB
  __shared__ __align__(16) float ep_lds[4][32 * 36];
  __shared__ float lsum_lds[QTJ];
  __shared__ __align__(16) float linv_lds[QTJ];

  // Bijective XCD swizzle: 512 blocks, 8 XCDs -> each XCD sees 2 consecutive b's
  const int L   = blockIdx.x;
  const int lin = (L & 7) * 64 + (L >> 3);
  const int b   = lin >> 5;
  const int j0  = (lin & 31) * QTJ;
  const int tid = threadIdx.x;
  const int lane = tid & 63;
  const int wid  = tid >> 6;      // 0..3
  const int l15  = lane & 15;
  const int lg   = lane >> 4;     // 0..3
  const int l31  = lane & 31;
  const int kh   = lane >> 5;     // 0..1
  const int c0   = wid * 128;     // PV channel slice
  const int prow_base = (wid * 16 + l15) * 64;

  // Q B-fragments for S (16x16): n=j=l15, k=d=lg*8+e
  short8 qf0, qf1;
  {
    const u16* qp = kq + (size_t)(b * Tc + j0 + wid * 16 + l15) * 128 + 64 + lg * 8;
    qf0 = *reinterpret_cast<const short8*>(qp);
    qf1 = *reinterpret_cast<const short8*>(qp + 32);
  }

  f32x16 O32[4][2];   // [ct][jt]: col j = jt*32+l31, row c via reg map -> 128 AGPR
  #pragma unroll
  for (int a = 0; a < 4; ++a)
    #pragma unroll
    for (int bb = 0; bb < 2; ++bb)
      #pragma unroll
      for (int e = 0; e < 16; ++e) O32[a][bb][e] = 0.f;

  float lsum = 0.f;

  const u16* kbase = kq + (size_t)b * Tc * 128 + lg * 8;
  const u16* vbase = vbf + ((size_t)b * Cc + c0) * Tc;

  short8 kf[4][2];       // K frags for next S tile
  short8 vf01[4][2];     // V B-frags ks 0..1 (i 0..31), prefetched cross-iter

  // ---- prologue: kf <- K(0); S(0) -> P[0]; kf <- K(1); vf01 <- V(0) ----
  #pragma unroll
  for (int it = 0; it < 4; ++it) {
    const u16* kp = kbase + (size_t)(it * 16 + l15) * 128;
    kf[it][0] = *reinterpret_cast<const short8*>(kp);
    kf[it][1] = *reinterpret_cast<const short8*>(kp + 32);
  }
  {
    f32x4 sacc[4];
    #pragma unroll
    for (int it = 0; it < 4; ++it) {
      f32x4 s = f32x4{0.f, 0.f, 0.f, 0.f};
      s = __builtin_amdgcn_mfma_f32_16x16x32_bf16(kf[it][0], qf0, s, 0, 0, 0);
      s = __builtin_amdgcn_mfma_f32_16x16x32_bf16(kf[it][1], qf1, s, 0, 0, 0);
      sacc[it] = s;
    }
    u16* prow = &P[0][prow_base];
    #pragma unroll
    for (int it = 0; it < 4; ++it) {
      float p0 = __expf(sacc[it][0]);
      float p1 = __expf(sacc[it][1]);
      float p2 = __expf(sacc[it][2]);
      float p3 = __expf(sacc[it][3]);
      lsum += (p0 + p1) + (p2 + p3);
      uint2 wv;
      wv.x = cvt_pk_bf16(p0, p1);
      wv.y = cvt_pk_bf16(p2, p3);
      int chk = ((it * 2 + (lg >> 1)) ^ (l15 & 7)) * 8 + (lg & 1) * 4;
      *reinterpret_cast<uint2*>(prow + chk) = wv;
    }
  }
  #pragma unroll
  for (int it = 0; it < 4; ++it) {
    const u16* kp = kbase + (size_t)(KT + it * 16 + l15) * 128;
    kf[it][0] = *reinterpret_cast<const short8*>(kp);
    kf[it][1] = *reinterpret_cast<const short8*>(kp + 32);
  }
  #pragma unroll
  for (int ct = 0; ct < 4; ++ct)
    #pragma unroll
    for (int kk = 0; kk < 2; ++kk)
      vf01[ct][kk] = *reinterpret_cast<const short8*>(
          vbase + (size_t)(ct * 32 + l31) * Tc + kk * 16 + kh * 8);
  block_sync_lds();

  int pb = 0;
  for (int i = 0; i < NT; ++i, pb ^= 1) {
    const int i0 = i * KT;
    const bool last = (i + 1 >= NT);

    // ---- S(i+1) + exp + publish P[pb^1] (sacc dies before PV) ----
    if (!last) {
      f32x4 sacc[4];
      #pragma unroll
      for (int it = 0; it < 4; ++it) {
        f32x4 s = f32x4{0.f, 0.f, 0.f, 0.f};
        s = __builtin_amdgcn_mfma_f32_16x16x32_bf16(kf[it][0], qf0, s, 0, 0, 0);
        s = __builtin_amdgcn_mfma_f32_16x16x32_bf16(kf[it][1], qf1, s, 0, 0, 0);
        sacc[it] = s;
      }
      u16* prow = &P[pb ^ 1][prow_base];
      #pragma unroll
      for (int it = 0; it < 4; ++it) {
        float p0 = __expf(sacc[it][0]);
        float p1 = __expf(sacc[it][1]);
        float p2 = __expf(sacc[it][2]);
        float p3 = __expf(sacc[it][3]);
        lsum += (p0 + p1) + (p2 + p3);
        uint2 wv;
        wv.x = cvt_pk_bf16(p0, p1);
        wv.y = cvt_pk_bf16(p2, p3);
        int chk = ((it * 2 + (lg >> 1)) ^ (l15 & 7)) * 8 + (lg & 1) * 4;
        *reinterpret_cast<uint2*>(prow + chk) = wv;
      }
    }

    // ---- PV(i): ks0/ks1 on prefetched vf01 while vf23 chunks load ----
    {
      // issue vf ks=2 chunk (16 regs)
      short8 vf2[4];
      #pragma unroll
      for (int ct = 0; ct < 4; ++ct)
        vf2[ct] = *reinterpret_cast<const short8*>(
            vbase + (size_t)(ct * 32 + l31) * Tc + i0 + 32 + kh * 8);

      #pragma unroll
      for (int ks = 0; ks < 2; ++ks) {
        short8 pf[2];
        #pragma unroll
        for (int jt = 0; jt < 2; ++jt) {
          int row = jt * 32 + l31;
          int chk = ((ks * 2 + kh) ^ (row & 7)) * 8;
          pf[jt] = *reinterpret_cast<const short8*>(&P[pb][row * 64 + chk]);
        }
        #pragma unroll
        for (int ct = 0; ct < 4; ++ct)
          #pragma unroll
          for (int jt = 0; jt < 2; ++jt)
            O32[ct][jt] = __builtin_amdgcn_mfma_f32_32x32x16_bf16(vf01[ct][ks], pf[jt], O32[ct][jt], 0, 0, 0);
      }

      // issue vf ks=3 chunk
      short8 vf3[4];
      #pragma unroll
      for (int ct = 0; ct < 4; ++ct)
        vf3[ct] = *reinterpret_cast<const short8*>(
            vbase + (size_t)(ct * 32 + l31) * Tc + i0 + 48 + kh * 8);

      {
        const int ks = 2;
        short8 pf[2];
        #pragma unroll
        for (int jt = 0; jt < 2; ++jt) {
          int row = jt * 32 + l31;
          int chk = ((ks * 2 + kh) ^ (row & 7)) * 8;
          pf[jt] = *reinterpret_cast<const short8*>(&P[pb][row * 64 + chk]);
        }
        #pragma unroll
        for (int ct = 0; ct < 4; ++ct)
          #pragma unroll
          for (int jt = 0; jt < 2; ++jt)
            O32[ct][jt] = __builtin_amdgcn_mfma_f32_32x32x16_bf16(vf2[ct], pf[jt], O32[ct][jt], 0, 0, 0);
      }
      // prefetch vf01 <- V(i+1) for next iter
      if (!last) {
        #pragma unroll
        for (int ct = 0; ct < 4; ++ct)
          #pragma unroll
          for (int kk = 0; kk < 2; ++kk)
            vf01[ct][kk] = *reinterpret_cast<const short8*>(
                vbase + (size_t)(ct * 32 + l31) * Tc + (i0 + KT) + kk * 16 + kh * 8);
      }
      {
        const int ks = 3;
        short8 pf[2];
        #pragma unroll
        for (int jt = 0; jt < 2; ++jt) {
          int row = jt * 32 + l31;
          int chk = ((ks * 2 + kh) ^ (row & 7)) * 8;
          pf[jt] = *reinterpret_cast<const short8*>(&P[pb][row * 64 + chk]);
        }
        #pragma unroll
        for (int ct = 0; ct < 4; ++ct)
          #pragma unroll
          for (int jt = 0; jt < 2; ++jt)
            O32[ct][jt] = __builtin_amdgcn_mfma_f32_32x32x16_bf16(vf3[ct], pf[jt], O32[ct][jt], 0, 0, 0);
      }
    }

    // ---- prefetch kf <- K(i+2) (kf dead during PV above) ----
    if (!last && (i + 2 < NT)) {
      #pragma unroll
      for (int it = 0; it < 4; ++it) {
        const u16* kp = kbase + (size_t)((i0 + 2 * KT) + it * 16 + l15) * 128;
        kf[it][0] = *reinterpret_cast<const short8*>(kp);
        kf[it][1] = *reinterpret_cast<const short8*>(kp + 32);
      }
    }
    if (!last) block_sync_lds();
  }

  // ---- denominators ----
  lsum += __shfl_xor(lsum, 16);
  lsum += __shfl_xor(lsum, 32);
  if (lane < 16) lsum_lds[wid * 16 + lane] = lsum;
  __syncthreads();
  const float gamma = *gamma_p;
  if (tid < QTJ) linv_lds[tid] = gamma / lsum_lds[tid];
  __syncthreads();

  // ---- epilogue: per-wave LDS transpose of each 32x32 tile, float4 I/O ----
  float* ep = ep_lds[wid];
  const int rd_row = lane >> 3;   // 0..7 (+8h)
  const int rd_ch  = lane & 7;    // j quad
  #pragma unroll
  for (int ct = 0; ct < 4; ++ct) {
    #pragma unroll
    for (int jt = 0; jt < 2; ++jt) {
      #pragma unroll
      for (int reg = 0; reg < 16; ++reg) {
        int cl = (reg & 3) + 8 * (reg >> 2) + 4 * kh;
        ep[cl * 36 + l31] = O32[ct][jt][reg];
      }
      asm volatile("s_waitcnt lgkmcnt(0)" ::: "memory");
      __builtin_amdgcn_sched_barrier(0);
      #pragma unroll
      for (int h = 0; h < 4; ++h) {
        const int row = rd_row + 8 * h;
        f32x4 o4 = *reinterpret_cast<const f32x4*>(&ep[row * 36 + rd_ch * 4]);
        const int jg = jt * 32 + rd_ch * 4;
        f32x4 li = *reinterpret_cast<const f32x4*>(&linv_lds[jg]);
        const int c_glob = c0 + ct * 32 + row;
        const float* vr = v + ((size_t)(b * Cc + c_glob)) * Tc + j0 + jg;
        float* orow = out + ((size_t)(b * Cc + c_glob)) * Tc + j0 + jg;
        f32x4 v4 = *reinterpret_cast<const f32x4*>(vr);
        f32x4 o;
        o[0] = v4[0] + li[0] * o4[0];
        o[1] = v4[1] + li[1] * o4[1];
        o[2] = v4[2] + li[2] * o4[2];
        o[3] = v4[3] + li[3] * o4[3];
        *reinterpret_cast<f32x4*>(orow) = o;
      }
      asm volatile("s_waitcnt lgkmcnt(0)" ::: "memory");
      __builtin_amdgcn_sched_barrier(0);
    }
  }
}

extern "C" void kernel_launch(void* const* d_in, const int* in_sizes, int n_in,
                              void* d_out, int out_size, void* d_ws, size_t ws_size,
                              hipStream_t stream) {
  const float* v  = (const float*)d_in[0];
  const float* Wk = (const float*)d_in[1];
  const float* bk = (const float*)d_in[2];
  const float* Wq = (const float*)d_in[3];
  const float* bq = (const float*)d_in[4];
  const float* gm = (const float*)d_in[5];
  float* out = (float*)d_out;

  char* ws = (char*)d_ws;
  u16*   kqb = (u16*)ws;                                   //  8,388,608 B
  u16*   vbf = (u16*)(ws + 8388608);                       // 33,554,432 B
  u16*   Wbf = (u16*)(ws + 8388608 + 33554432);            //    131,072 B
  float* bkq = (float*)(ws + 8388608 + 33554432 + 131072); //        512 B

  prep_kernel<<<dim3(64), dim3(256), 0, stream>>>(Wk, Wq, bk, bq, Wbf, bkq);
  kqv_kernel<<<dim3(Tc / 64, Bc), dim3(256), 0, stream>>>(v, Wbf, bkq, kqb, vbf);
  attn_kernel<<<dim3((Tc / QTJ) * Bc), dim3(256), 0, stream>>>(v, vbf, kqb, gm, out);
}

// Round 17
// 161.062 us; speedup vs baseline: 2.7084x; 1.4949x over previous
//
#include <hip/hip_runtime.h>

#define Bc 16
#define Cc 512
#define Tc 2048
#define QT 128
#define KT 64
#define NT 32     // Tc / KT
#define LTS 66    // kqv LDS transposed-tile row stride (ushort), 64+2 pad

typedef __attribute__((ext_vector_type(8)))  short short8;
typedef __attribute__((ext_vector_type(4)))  float f32x4;
typedef __attribute__((ext_vector_type(16))) float f32x16;
typedef unsigned short u16;

static __device__ __forceinline__ u16 f2bf(float x) {
  unsigned u = __float_as_uint(x);
  u += 0x7FFF + ((u >> 16) & 1);   // RNE
  return (u16)(u >> 16);
}

// Pack 2 f32 -> 2 bf16 in one VALU op (no builtin on gfx950).
static __device__ __forceinline__ unsigned cvt_pk_bf16(float lo, float hi) {
  unsigned r;
  asm("v_cvt_pk_bf16_f32 %0, %1, %2" : "=v"(r) : "v"(lo), "v"(hi));
  return r;
}

// Async global->LDS, 16B per lane: LDS dest = wave-uniform base + lane*16.
static __device__ __forceinline__ void gload_lds16(const u16* gsrc, u16* ldst) {
  __builtin_amdgcn_global_load_lds(
      (const __attribute__((address_space(1))) unsigned int*)gsrc,
      (__attribute__((address_space(3))) unsigned int*)ldst,
      16, 0, 0);
}

// Barrier that waits ONLY on LDS ops (used in kqv).
static __device__ __forceinline__ void block_sync_lds() {
  __builtin_amdgcn_sched_barrier(0);
  asm volatile("s_waitcnt lgkmcnt(0)" ::: "memory");
  __builtin_amdgcn_s_barrier();
  __builtin_amdgcn_sched_barrier(0);
}

// ---------------- Kernel 0: W -> bf16 (fused k||q), bias -> bkq ----------------
__global__ __launch_bounds__(256) void prep_kernel(
    const float* __restrict__ Wk, const float* __restrict__ Wq,
    const float* __restrict__ bk, const float* __restrict__ bq,
    u16* __restrict__ Wbf, float* __restrict__ bkq)
{
  int idx  = blockIdx.x * 256 + threadIdx.x;
  int base = idx * 4;
  if (base < 128 * Cc) {
    int ch = base >> 9;
    int c  = base & (Cc - 1);
    const float* src = (ch < 64) ? (Wk + (size_t)ch * Cc + c)
                                 : (Wq + (size_t)(ch - 64) * Cc + c);
    f32x4 w = *reinterpret_cast<const f32x4*>(src);
    uint2 o;
    o.x = (unsigned)f2bf(w[0]) | ((unsigned)f2bf(w[1]) << 16);
    o.y = (unsigned)f2bf(w[2]) | ((unsigned)f2bf(w[3]) << 16);
    *reinterpret_cast<uint2*>(Wbf + base) = o;
  }
  if (idx < 128) bkq[idx] = (idx < 64) ? bk[idx] : bq[idx - 64];
}

// ---------------- Kernel 1: kq[t][ch] via MFMA + vbf16 emission ----------------
__global__ __launch_bounds__(256) void kqv_kernel(
    const float* __restrict__ v, const u16* __restrict__ Wbf,
    const float* __restrict__ bkq, u16* __restrict__ kq, u16* __restrict__ vbf)
{
  __shared__ u16 LDSt[2][64][LTS];
  const int b   = blockIdx.y;
  const int t0  = blockIdx.x * 64;
  const int tid = threadIdx.x;
  const int lane = tid & 63;
  const int w    = tid >> 6;
  const int l15  = lane & 15;
  const int lg   = lane >> 4;

  f32x4 acc[8];
  #pragma unroll
  for (int mt = 0; mt < 8; ++mt) acc[mt] = f32x4{0.f, 0.f, 0.f, 0.f};

  const float* vb = v + (size_t)b * Cc * Tc + t0;
  float x[16];
  #pragma unroll
  for (int r = 0; r < 16; ++r) x[r] = vb[(size_t)(w * 16 + r) * Tc + lane];

  int buf = 0;
  for (int c0 = 0; c0 < Cc; c0 += 64, buf ^= 1) {
    #pragma unroll
    for (int r = 0; r < 16; ++r) {
      u16 hb = f2bf(x[r]);
      LDSt[buf][lane][w * 16 + r] = hb;
      vbf[((size_t)b * Cc + c0 + w * 16 + r) * Tc + t0 + lane] = hb;
    }
    block_sync_lds();
    if (c0 + 64 < Cc) {
      #pragma unroll
      for (int r = 0; r < 16; ++r)
        x[r] = vb[(size_t)(c0 + 64 + w * 16 + r) * Tc + lane];
    }
    #pragma unroll
    for (int ks = 0; ks < 2; ++ks) {
      short8 bfrag = *reinterpret_cast<const short8*>(&LDSt[buf][w * 16 + l15][ks * 32 + lg * 8]);
      #pragma unroll
      for (int mt = 0; mt < 8; ++mt) {
        short8 afrag = *reinterpret_cast<const short8*>(
            Wbf + (size_t)(mt * 16 + l15) * Cc + c0 + ks * 32 + lg * 8);
        acc[mt] = __builtin_amdgcn_mfma_f32_16x16x32_bf16(afrag, bfrag, acc[mt], 0, 0, 0);
      }
    }
  }
  const int t = t0 + w * 16 + l15;
  u16* op = kq + ((size_t)b * Tc + t) * 128;
  #pragma unroll
  for (int mt = 0; mt < 8; ++mt) {
    int chb = mt * 16 + lg * 4;
    uint2 o;
    o.x = cvt_pk_bf16(acc[mt][0] + bkq[chb + 0], acc[mt][1] + bkq[chb + 1]);
    o.y = cvt_pk_bf16(acc[mt][2] + bkq[chb + 2], acc[mt][3] + bkq[chb + 3]);
    *reinterpret_cast<uint2*>(op + chb) = o;
  }
}

// ---------------- Kernel 2: r14 structure + K staged once via global_load_lds ----------------
// K(t) lives in Klds[t&1] (64 i x 64 ch bf16, 128 B rows, chunk XOR-swizzled via
// pre-swizzled GLOBAL source — rule #21: linear LDS dest + inverse-swz src + swz read).
// One gload_lds dwordx4 per wave per iter stages the whole block's K tile (was 8
// redundant b128 VMEM loads per wave). Full __syncthreads fences the vmcnt.
__global__ __launch_bounds__(512, 2) void attn_kernel(
    const float* __restrict__ v, const u16* __restrict__ vbf,
    const u16* __restrict__ kq, const float* __restrict__ gamma_p,
    float* __restrict__ out)
{
  __shared__ u16 P[2][128 * 64];        // 32 KB, swizzled (r14 layout)
  __shared__ u16 Klds[2][64 * 64];      // 16 KB, K tiles, swizzled
  __shared__ __align__(16) float ep_lds[8][32 * 36];
  __shared__ float lsum_lds[QT];
  __shared__ __align__(16) float linv_lds[QT];

  // XCD-aware swizzle: 256 blocks, 8 XCDs -> each XCD sees 2 consecutive b's
  const int L   = blockIdx.x;
  const int lin = (L & 7) * 32 + (L >> 3);
  const int b   = lin >> 4;
  const int j0  = (lin & 15) * QT;
  const int tid = threadIdx.x;
  const int lane = tid & 63;
  const int wid  = tid >> 6;      // 0..7 = owned j-tile (S) AND 64-channel slice (PV)
  const int l15  = lane & 15;
  const int lg   = lane >> 4;     // 0..3
  const int l31  = lane & 31;
  const int kh   = lane >> 5;     // 0..1
  const int c0   = wid * 64;

  // K staging addressing: wave stages rows wid*8..wid*8+7 of the 64-row tile.
  const int sr = wid * 8 + (lane >> 3);                 // tile-local row
  const int sc = (lane & 7) ^ ((lane >> 3) & 7);        // pre-swizzled 16B chunk
  const u16* kqb2 = kq + (size_t)b * Tc * 128;
  u16* kst_dst = &Klds[0][0] + wid * 8 * 64;            // + buf*4096 at use

  // Q B-fragments for S (16x16): n=j=l15, k=d=lg*8+e
  short8 qf0, qf1;
  {
    const u16* qp = kq + (size_t)(b * Tc + j0 + wid * 16 + l15) * 128 + 64 + lg * 8;
    qf0 = *reinterpret_cast<const short8*>(qp);
    qf1 = *reinterpret_cast<const short8*>(qp + 32);
  }

  f32x16 O32[2][4];   // [ct][jt]: col j = jt*32+l31, row c via reg map -> 128 AGPR
  #pragma unroll
  for (int a = 0; a < 2; ++a)
    #pragma unroll
    for (int bb = 0; bb < 4; ++bb)
      #pragma unroll
      for (int e = 0; e < 16; ++e) O32[a][bb][e] = 0.f;

  float lsum = 0.f;

  const u16* vbase = vbf + ((size_t)b * Cc + c0) * Tc;
  short8 vf0[2][2];      // V A-frags ks 0..1 (i 0..31), prefetched cross-iter

  // ---- prologue: stage K(0); S(0)->P[0]; stage K(1); prefetch vf0(0) ----
  gload_lds16(kqb2 + (size_t)sr * 128 + sc * 8, kst_dst + 0 * 4096);
  __syncthreads();
  {
    short8 kf[4][2];
    #pragma unroll
    for (int it = 0; it < 4; ++it)
      #pragma unroll
      for (int ks = 0; ks < 2; ++ks)
        kf[it][ks] = *reinterpret_cast<const short8*>(
            &Klds[0][(it * 16 + l15) * 64 + (((ks * 4 + lg) ^ (l15 & 7)) * 8)]);
    f32x4 sacc[4];
    #pragma unroll
    for (int it = 0; it < 4; ++it) {
      f32x4 s = f32x4{0.f, 0.f, 0.f, 0.f};
      s = __builtin_amdgcn_mfma_f32_16x16x32_bf16(kf[it][0], qf0, s, 0, 0, 0);
      s = __builtin_amdgcn_mfma_f32_16x16x32_bf16(kf[it][1], qf1, s, 0, 0, 0);
      sacc[it] = s;
    }
    u16* prow = &P[0][(wid * 16 + l15) * 64];
    #pragma unroll
    for (int it = 0; it < 4; ++it) {
      float p0 = __expf(sacc[it][0]);
      float p1 = __expf(sacc[it][1]);
      float p2 = __expf(sacc[it][2]);
      float p3 = __expf(sacc[it][3]);
      lsum += (p0 + p1) + (p2 + p3);
      uint2 wv;
      wv.x = cvt_pk_bf16(p0, p1);
      wv.y = cvt_pk_bf16(p2, p3);
      int chk = ((it * 2 + (lg >> 1)) ^ (l15 & 7)) * 8 + (lg & 1) * 4;
      *reinterpret_cast<uint2*>(prow + chk) = wv;
    }
  }
  gload_lds16(kqb2 + (size_t)(KT + sr) * 128 + sc * 8, kst_dst + 1 * 4096);
  #pragma unroll
  for (int ct = 0; ct < 2; ++ct)
    #pragma unroll
    for (int kk = 0; kk < 2; ++kk)
      vf0[ct][kk] = *reinterpret_cast<const short8*>(
          vbase + (size_t)(ct * 32 + l31) * Tc + kk * 16 + kh * 8);
  __syncthreads();

  int pb = 0;
  for (int i = 0; i < NT; ++i, pb ^= 1) {
    const int i0 = i * KT;
    const bool last = (i + 1 >= NT);

    // ---- stage K(i+2) -> Klds[i&1] (read region i+1; fenced by next barrier) ----
    if (i + 2 < NT)
      gload_lds16(kqb2 + (size_t)(i0 + 2 * KT + sr) * 128 + sc * 8,
                  kst_dst + (i & 1) * 4096);

    // ---- V A-frags ks 2..3 for tile i: issued early ----
    short8 vf1[2][2];
    #pragma unroll
    for (int ct = 0; ct < 2; ++ct)
      #pragma unroll
      for (int kk = 0; kk < 2; ++kk)
        vf1[ct][kk] = *reinterpret_cast<const short8*>(
            vbase + (size_t)(ct * 32 + l31) * Tc + i0 + 32 + kk * 16 + kh * 8);

    // ---- S(i+1) from Klds[(i+1)&1] + exp + publish P[pb^1] ----
    if (!last) {
      short8 kf[4][2];
      #pragma unroll
      for (int it = 0; it < 4; ++it)
        #pragma unroll
        for (int ks = 0; ks < 2; ++ks)
          kf[it][ks] = *reinterpret_cast<const short8*>(
              &Klds[(i + 1) & 1][(it * 16 + l15) * 64 + (((ks * 4 + lg) ^ (l15 & 7)) * 8)]);
      f32x4 sacc[4];
      #pragma unroll
      for (int it = 0; it < 4; ++it) {
        f32x4 s = f32x4{0.f, 0.f, 0.f, 0.f};
        s = __builtin_amdgcn_mfma_f32_16x16x32_bf16(kf[it][0], qf0, s, 0, 0, 0);
        s = __builtin_amdgcn_mfma_f32_16x16x32_bf16(kf[it][1], qf1, s, 0, 0, 0);
        sacc[it] = s;
      }
      u16* prow = &P[pb ^ 1][(wid * 16 + l15) * 64];
      #pragma unroll
      for (int it = 0; it < 4; ++it) {
        float p0 = __expf(sacc[it][0]);
        float p1 = __expf(sacc[it][1]);
        float p2 = __expf(sacc[it][2]);
        float p3 = __expf(sacc[it][3]);
        lsum += (p0 + p1) + (p2 + p3);
        uint2 wv;
        wv.x = cvt_pk_bf16(p0, p1);
        wv.y = cvt_pk_bf16(p2, p3);
        int chk = ((it * 2 + (lg >> 1)) ^ (l15 & 7)) * 8 + (lg & 1) * 4;
        *reinterpret_cast<uint2*>(prow + chk) = wv;
      }
    }

    // ---- PV(i): O[c][j] += V[c,i] P[i,j] via 32x32x16 ----
    #pragma unroll
    for (int ks = 0; ks < 4; ++ks) {
      short8 pf[4];
      #pragma unroll
      for (int jt = 0; jt < 4; ++jt) {
        int row = jt * 32 + l31;
        int chk = ((ks * 2 + kh) ^ (row & 7)) * 8;
        pf[jt] = *reinterpret_cast<const short8*>(&P[pb][row * 64 + chk]);
      }
      const short8* vsel0 = (ks < 2) ? &vf0[0][ks] : &vf1[0][ks - 2];
      const short8* vsel1 = (ks < 2) ? &vf0[1][ks] : &vf1[1][ks - 2];
      #pragma unroll
      for (int jt = 0; jt < 4; ++jt) {
        O32[0][jt] = __builtin_amdgcn_mfma_f32_32x32x16_bf16(*vsel0, pf[jt], O32[0][jt], 0, 0, 0);
        O32[1][jt] = __builtin_amdgcn_mfma_f32_32x32x16_bf16(*vsel1, pf[jt], O32[1][jt], 0, 0, 0);
      }
    }

    // ---- prefetch vf0(i+1) ----
    if (!last) {
      #pragma unroll
      for (int ct = 0; ct < 2; ++ct)
        #pragma unroll
        for (int kk = 0; kk < 2; ++kk)
          vf0[ct][kk] = *reinterpret_cast<const short8*>(
              vbase + (size_t)(ct * 32 + l31) * Tc + (i0 + KT) + kk * 16 + kh * 8);
      __syncthreads();   // fences P-write, K-stage vmcnt, LDS reads
    }
  }

  // ---- denominators ----
  lsum += __shfl_xor(lsum, 16);
  lsum += __shfl_xor(lsum, 32);
  if (lane < 16) lsum_lds[wid * 16 + lane] = lsum;
  __syncthreads();
  const float gamma = *gamma_p;
  if (tid < QT) linv_lds[tid] = gamma / lsum_lds[tid];
  __syncthreads();

  // ---- epilogue: per-wave LDS transpose of each 32x32 tile, float4 I/O ----
  float* ep = ep_lds[wid];
  const int rd_row = lane >> 3;   // 0..7 (+8h)
  const int rd_ch  = lane & 7;    // j quad
  #pragma unroll
  for (int ct = 0; ct < 2; ++ct) {
    #pragma unroll
    for (int jt = 0; jt < 4; ++jt) {
      #pragma unroll
      for (int reg = 0; reg < 16; ++reg) {
        int cl = (reg & 3) + 8 * (reg >> 2) + 4 * kh;
        ep[cl * 36 + l31] = O32[ct][jt][reg];
      }
      asm volatile("s_waitcnt lgkmcnt(0)" ::: "memory");
      __builtin_amdgcn_sched_barrier(0);
      #pragma unroll
      for (int h = 0; h < 4; ++h) {
        const int row = rd_row + 8 * h;
        f32x4 o4 = *reinterpret_cast<const f32x4*>(&ep[row * 36 + rd_ch * 4]);
        const int jg = jt * 32 + rd_ch * 4;
        f32x4 li = *reinterpret_cast<const f32x4*>(&linv_lds[jg]);
        const int c_glob = c0 + ct * 32 + row;
        const float* vr = v + ((size_t)(b * Cc + c_glob)) * Tc + j0 + jg;
        float* orow = out + ((size_t)(b * Cc + c_glob)) * Tc + j0 + jg;
        f32x4 v4 = *reinterpret_cast<const f32x4*>(vr);
        f32x4 o;
        o[0] = v4[0] + li[0] * o4[0];
        o[1] = v4[1] + li[1] * o4[1];
        o[2] = v4[2] + li[2] * o4[2];
        o[3] = v4[3] + li[3] * o4[3];
        *reinterpret_cast<f32x4*>(orow) = o;
      }
      asm volatile("s_waitcnt lgkmcnt(0)" ::: "memory");
      __builtin_amdgcn_sched_barrier(0);
    }
  }
}

extern "C" void kernel_launch(void* const* d_in, const int* in_sizes, int n_in,
                              void* d_out, int out_size, void* d_ws, size_t ws_size,
                              hipStream_t stream) {
  const float* v  = (const float*)d_in[0];
  const float* Wk = (const float*)d_in[1];
  const float* bk = (const float*)d_in[2];
  const float* Wq = (const float*)d_in[3];
  const float* bq = (const float*)d_in[4];
  const float* gm = (const float*)d_in[5];
  float* out = (float*)d_out;

  char* ws = (char*)d_ws;
  u16*   kqb = (u16*)ws;                                   //  8,388,608 B
  u16*   vbf = (u16*)(ws + 8388608);                       // 33,554,432 B
  u16*   Wbf = (u16*)(ws + 8388608 + 33554432);            //    131,072 B
  float* bkq = (float*)(ws + 8388608 + 33554432 + 131072); //        512 B

  prep_kernel<<<dim3(64), dim3(256), 0, stream>>>(Wk, Wq, bk, bq, Wbf, bkq);
  kqv_kernel<<<dim3(Tc / 64, Bc), dim3(256), 0, stream>>>(v, Wbf, bkq, kqb, vbf);
  attn_kernel<<<dim3((Tc / QT) * Bc), dim3(512), 0, stream>>>(v, vbf, kqb, gm, out);
}

// Round 18
// 157.212 us; speedup vs baseline: 2.7747x; 1.0245x over previous
//
#include <hip/hip_runtime.h>

#define Bc 16
#define Cc 512
#define Tc 2048
#define QT 128
#define KT 64
#define NT 32     // Tc / KT
#define LTS 66    // kqv LDS transposed-tile row stride (ushort), 64+2 pad

typedef __attribute__((ext_vector_type(8)))  short short8;
typedef __attribute__((ext_vector_type(4)))  float f32x4;
typedef __attribute__((ext_vector_type(16))) float f32x16;
typedef unsigned short u16;

static __device__ __forceinline__ u16 f2bf(float x) {
  unsigned u = __float_as_uint(x);
  u += 0x7FFF + ((u >> 16) & 1);   // RNE
  return (u16)(u >> 16);
}

// Pack 2 f32 -> 2 bf16 in one VALU op (no builtin on gfx950).
static __device__ __forceinline__ unsigned cvt_pk_bf16(float lo, float hi) {
  unsigned r;
  asm("v_cvt_pk_bf16_f32 %0, %1, %2" : "=v"(r) : "v"(lo), "v"(hi));
  return r;
}

// Async global->LDS, 16B per lane: LDS dest = wave-uniform base + lane*16.
static __device__ __forceinline__ void gload_lds16(const u16* gsrc, u16* ldst) {
  __builtin_amdgcn_global_load_lds(
      (const __attribute__((address_space(1))) unsigned int*)gsrc,
      (__attribute__((address_space(3))) unsigned int*)ldst,
      16, 0, 0);
}

// Barrier that waits ONLY on LDS ops (used in kqv).
static __device__ __forceinline__ void block_sync_lds() {
  __builtin_amdgcn_sched_barrier(0);
  asm volatile("s_waitcnt lgkmcnt(0)" ::: "memory");
  __builtin_amdgcn_s_barrier();
  __builtin_amdgcn_sched_barrier(0);
}

// T4 counted barrier: drain LDS ops + all VMEM older than the newest 4
// (the vf0 prefetch) — K-stage forced complete, vf0 stays in flight.
static __device__ __forceinline__ void block_sync_vm4() {
  __builtin_amdgcn_sched_barrier(0);
  asm volatile("s_waitcnt vmcnt(4) lgkmcnt(0)" ::: "memory");
  __builtin_amdgcn_s_barrier();
  __builtin_amdgcn_sched_barrier(0);
}

// ---------------- Kernel 0: W -> bf16 (fused k||q), bias -> bkq ----------------
__global__ __launch_bounds__(256) void prep_kernel(
    const float* __restrict__ Wk, const float* __restrict__ Wq,
    const float* __restrict__ bk, const float* __restrict__ bq,
    u16* __restrict__ Wbf, float* __restrict__ bkq)
{
  int idx  = blockIdx.x * 256 + threadIdx.x;
  int base = idx * 4;
  if (base < 128 * Cc) {
    int ch = base >> 9;
    int c  = base & (Cc - 1);
    const float* src = (ch < 64) ? (Wk + (size_t)ch * Cc + c)
                                 : (Wq + (size_t)(ch - 64) * Cc + c);
    f32x4 w = *reinterpret_cast<const f32x4*>(src);
    uint2 o;
    o.x = (unsigned)f2bf(w[0]) | ((unsigned)f2bf(w[1]) << 16);
    o.y = (unsigned)f2bf(w[2]) | ((unsigned)f2bf(w[3]) << 16);
    *reinterpret_cast<uint2*>(Wbf + base) = o;
  }
  if (idx < 128) bkq[idx] = (idx < 64) ? bk[idx] : bq[idx - 64];
}

// ---------------- Kernel 1: kq[t][ch] via MFMA + vbf16 emission ----------------
__global__ __launch_bounds__(256) void kqv_kernel(
    const float* __restrict__ v, const u16* __restrict__ Wbf,
    const float* __restrict__ bkq, u16* __restrict__ kq, u16* __restrict__ vbf)
{
  __shared__ u16 LDSt[2][64][LTS];
  const int b   = blockIdx.y;
  const int t0  = blockIdx.x * 64;
  const int tid = threadIdx.x;
  const int lane = tid & 63;
  const int w    = tid >> 6;
  const int l15  = lane & 15;
  const int lg   = lane >> 4;

  f32x4 acc[8];
  #pragma unroll
  for (int mt = 0; mt < 8; ++mt) acc[mt] = f32x4{0.f, 0.f, 0.f, 0.f};

  const float* vb = v + (size_t)b * Cc * Tc + t0;
  float x[16];
  #pragma unroll
  for (int r = 0; r < 16; ++r) x[r] = vb[(size_t)(w * 16 + r) * Tc + lane];

  int buf = 0;
  for (int c0 = 0; c0 < Cc; c0 += 64, buf ^= 1) {
    #pragma unroll
    for (int r = 0; r < 16; ++r) {
      u16 hb = f2bf(x[r]);
      LDSt[buf][lane][w * 16 + r] = hb;
      vbf[((size_t)b * Cc + c0 + w * 16 + r) * Tc + t0 + lane] = hb;
    }
    block_sync_lds();
    if (c0 + 64 < Cc) {
      #pragma unroll
      for (int r = 0; r < 16; ++r)
        x[r] = vb[(size_t)(c0 + 64 + w * 16 + r) * Tc + lane];
    }
    #pragma unroll
    for (int ks = 0; ks < 2; ++ks) {
      short8 bfrag = *reinterpret_cast<const short8*>(&LDSt[buf][w * 16 + l15][ks * 32 + lg * 8]);
      #pragma unroll
      for (int mt = 0; mt < 8; ++mt) {
        short8 afrag = *reinterpret_cast<const short8*>(
            Wbf + (size_t)(mt * 16 + l15) * Cc + c0 + ks * 32 + lg * 8);
        acc[mt] = __builtin_amdgcn_mfma_f32_16x16x32_bf16(afrag, bfrag, acc[mt], 0, 0, 0);
      }
    }
  }
  const int t = t0 + w * 16 + l15;
  u16* op = kq + ((size_t)b * Tc + t) * 128;
  #pragma unroll
  for (int mt = 0; mt < 8; ++mt) {
    int chb = mt * 16 + lg * 4;
    uint2 o;
    o.x = cvt_pk_bf16(acc[mt][0] + bkq[chb + 0], acc[mt][1] + bkq[chb + 1]);
    o.y = cvt_pk_bf16(acc[mt][2] + bkq[chb + 2], acc[mt][3] + bkq[chb + 3]);
    *reinterpret_cast<uint2*>(op + chb) = o;
  }
}

// ---------------- Kernel 2: r17 + counted-vmcnt barrier (vf0 stays in flight) ----------------
__global__ __launch_bounds__(512, 2) void attn_kernel(
    const float* __restrict__ v, const u16* __restrict__ vbf,
    const u16* __restrict__ kq, const float* __restrict__ gamma_p,
    float* __restrict__ out)
{
  __shared__ u16 P[2][128 * 64];        // 32 KB, swizzled (r14 layout)
  __shared__ u16 Klds[2][64 * 64];      // 16 KB, K tiles, swizzled
  __shared__ __align__(16) float ep_lds[8][32 * 36];
  __shared__ float lsum_lds[QT];
  __shared__ __align__(16) float linv_lds[QT];

  // XCD-aware swizzle: 256 blocks, 8 XCDs -> each XCD sees 2 consecutive b's
  const int L   = blockIdx.x;
  const int lin = (L & 7) * 32 + (L >> 3);
  const int b   = lin >> 4;
  const int j0  = (lin & 15) * QT;
  const int tid = threadIdx.x;
  const int lane = tid & 63;
  const int wid  = tid >> 6;      // 0..7 = owned j-tile (S) AND 64-channel slice (PV)
  const int l15  = lane & 15;
  const int lg   = lane >> 4;     // 0..3
  const int l31  = lane & 31;
  const int kh   = lane >> 5;     // 0..1
  const int c0   = wid * 64;

  // K staging addressing: wave stages rows wid*8..wid*8+7 of the 64-row tile.
  const int sr = wid * 8 + (lane >> 3);                 // tile-local row
  const int sc = (lane & 7) ^ ((lane >> 3) & 7);        // pre-swizzled 16B chunk
  const u16* kqb2 = kq + (size_t)b * Tc * 128;
  u16* kst_dst = &Klds[0][0] + wid * 8 * 64;            // + buf*4096 at use

  // Q B-fragments for S (16x16): n=j=l15, k=d=lg*8+e
  short8 qf0, qf1;
  {
    const u16* qp = kq + (size_t)(b * Tc + j0 + wid * 16 + l15) * 128 + 64 + lg * 8;
    qf0 = *reinterpret_cast<const short8*>(qp);
    qf1 = *reinterpret_cast<const short8*>(qp + 32);
  }

  f32x16 O32[2][4];   // [ct][jt]: col j = jt*32+l31, row c via reg map -> 128 AGPR
  #pragma unroll
  for (int a = 0; a < 2; ++a)
    #pragma unroll
    for (int bb = 0; bb < 4; ++bb)
      #pragma unroll
      for (int e = 0; e < 16; ++e) O32[a][bb][e] = 0.f;

  float lsum = 0.f;

  const u16* vbase = vbf + ((size_t)b * Cc + c0) * Tc;
  short8 vf0[2][2];      // V A-frags ks 0..1 (i 0..31), prefetched cross-iter

  // ---- prologue: stage K(0); S(0)->P[0]; stage K(1); prefetch vf0(0) ----
  gload_lds16(kqb2 + (size_t)sr * 128 + sc * 8, kst_dst + 0 * 4096);
  __syncthreads();
  {
    short8 kf[4][2];
    #pragma unroll
    for (int it = 0; it < 4; ++it)
      #pragma unroll
      for (int ks = 0; ks < 2; ++ks)
        kf[it][ks] = *reinterpret_cast<const short8*>(
            &Klds[0][(it * 16 + l15) * 64 + (((ks * 4 + lg) ^ (l15 & 7)) * 8)]);
    f32x4 sacc[4];
    #pragma unroll
    for (int it = 0; it < 4; ++it) {
      f32x4 s = f32x4{0.f, 0.f, 0.f, 0.f};
      s = __builtin_amdgcn_mfma_f32_16x16x32_bf16(kf[it][0], qf0, s, 0, 0, 0);
      s = __builtin_amdgcn_mfma_f32_16x16x32_bf16(kf[it][1], qf1, s, 0, 0, 0);
      sacc[it] = s;
    }
    u16* prow = &P[0][(wid * 16 + l15) * 64];
    #pragma unroll
    for (int it = 0; it < 4; ++it) {
      float p0 = __expf(sacc[it][0]);
      float p1 = __expf(sacc[it][1]);
      float p2 = __expf(sacc[it][2]);
      float p3 = __expf(sacc[it][3]);
      lsum += (p0 + p1) + (p2 + p3);
      uint2 wv;
      wv.x = cvt_pk_bf16(p0, p1);
      wv.y = cvt_pk_bf16(p2, p3);
      int chk = ((it * 2 + (lg >> 1)) ^ (l15 & 7)) * 8 + (lg & 1) * 4;
      *reinterpret_cast<uint2*>(prow + chk) = wv;
    }
  }
  gload_lds16(kqb2 + (size_t)(KT + sr) * 128 + sc * 8, kst_dst + 1 * 4096);
  #pragma unroll
  for (int ct = 0; ct < 2; ++ct)
    #pragma unroll
    for (int kk = 0; kk < 2; ++kk)
      vf0[ct][kk] = *reinterpret_cast<const short8*>(
          vbase + (size_t)(ct * 32 + l31) * Tc + kk * 16 + kh * 8);
  block_sync_vm4();   // K(1) drained (older than vf0), vf0 stays in flight

  int pb = 0;
  for (int i = 0; i < NT; ++i, pb ^= 1) {
    const int i0 = i * KT;
    const bool last = (i + 1 >= NT);

    // ---- V A-frags ks 2..3 for tile i: issued first (oldest after barrier) ----
    short8 vf1[2][2];
    #pragma unroll
    for (int ct = 0; ct < 2; ++ct)
      #pragma unroll
      for (int kk = 0; kk < 2; ++kk)
        vf1[ct][kk] = *reinterpret_cast<const short8*>(
            vbase + (size_t)(ct * 32 + l31) * Tc + i0 + 32 + kk * 16 + kh * 8);

    // ---- stage K(i+2) -> Klds[i&1] (must complete by END of this iter) ----
    if (i + 2 < NT)
      gload_lds16(kqb2 + (size_t)(i0 + 2 * KT + sr) * 128 + sc * 8,
                  kst_dst + (i & 1) * 4096);

    // ---- S(i+1) from Klds[(i+1)&1] + exp + publish P[pb^1] ----
    if (!last) {
      short8 kf[4][2];
      #pragma unroll
      for (int it = 0; it < 4; ++it)
        #pragma unroll
        for (int ks = 0; ks < 2; ++ks)
          kf[it][ks] = *reinterpret_cast<const short8*>(
              &Klds[(i + 1) & 1][(it * 16 + l15) * 64 + (((ks * 4 + lg) ^ (l15 & 7)) * 8)]);
      f32x4 sacc[4];
      #pragma unroll
      for (int it = 0; it < 4; ++it) {
        f32x4 s = f32x4{0.f, 0.f, 0.f, 0.f};
        s = __builtin_amdgcn_mfma_f32_16x16x32_bf16(kf[it][0], qf0, s, 0, 0, 0);
        s = __builtin_amdgcn_mfma_f32_16x16x32_bf16(kf[it][1], qf1, s, 0, 0, 0);
        sacc[it] = s;
      }
      u16* prow = &P[pb ^ 1][(wid * 16 + l15) * 64];
      #pragma unroll
      for (int it = 0; it < 4; ++it) {
        float p0 = __expf(sacc[it][0]);
        float p1 = __expf(sacc[it][1]);
        float p2 = __expf(sacc[it][2]);
        float p3 = __expf(sacc[it][3]);
        lsum += (p0 + p1) + (p2 + p3);
        uint2 wv;
        wv.x = cvt_pk_bf16(p0, p1);
        wv.y = cvt_pk_bf16(p2, p3);
        int chk = ((it * 2 + (lg >> 1)) ^ (l15 & 7)) * 8 + (lg & 1) * 4;
        *reinterpret_cast<uint2*>(prow + chk) = wv;
      }
    }

    // ---- PV(i): O[c][j] += V[c,i] P[i,j] via 32x32x16 ----
    #pragma unroll
    for (int ks = 0; ks < 4; ++ks) {
      short8 pf[4];
      #pragma unroll
      for (int jt = 0; jt < 4; ++jt) {
        int row = jt * 32 + l31;
        int chk = ((ks * 2 + kh) ^ (row & 7)) * 8;
        pf[jt] = *reinterpret_cast<const short8*>(&P[pb][row * 64 + chk]);
      }
      const short8* vsel0 = (ks < 2) ? &vf0[0][ks] : &vf1[0][ks - 2];
      const short8* vsel1 = (ks < 2) ? &vf0[1][ks] : &vf1[1][ks - 2];
      #pragma unroll
      for (int jt = 0; jt < 4; ++jt) {
        O32[0][jt] = __builtin_amdgcn_mfma_f32_32x32x16_bf16(*vsel0, pf[jt], O32[0][jt], 0, 0, 0);
        O32[1][jt] = __builtin_amdgcn_mfma_f32_32x32x16_bf16(*vsel1, pf[jt], O32[1][jt], 0, 0, 0);
      }
    }

    // ---- prefetch vf0(i+1): newest 4 VMEM ops — stay in flight across barrier ----
    if (!last) {
      #pragma unroll
      for (int ct = 0; ct < 2; ++ct)
        #pragma unroll
        for (int kk = 0; kk < 2; ++kk)
          vf0[ct][kk] = *reinterpret_cast<const short8*>(
              vbase + (size_t)(ct * 32 + l31) * Tc + (i0 + KT) + kk * 16 + kh * 8);
      block_sync_vm4();   // K(i+2) drained, vf0(i+1) stays outstanding
    }
  }

  // ---- denominators ----
  lsum += __shfl_xor(lsum, 16);
  lsum += __shfl_xor(lsum, 32);
  if (lane < 16) lsum_lds[wid * 16 + lane] = lsum;
  __syncthreads();
  const float gamma = *gamma_p;
  if (tid < QT) linv_lds[tid] = gamma / lsum_lds[tid];
  __syncthreads();

  // ---- epilogue: per-wave LDS transpose of each 32x32 tile, float4 I/O ----
  float* ep = ep_lds[wid];
  const int rd_row = lane >> 3;   // 0..7 (+8h)
  const int rd_ch  = lane & 7;    // j quad
  #pragma unroll
  for (int ct = 0; ct < 2; ++ct) {
    #pragma unroll
    for (int jt = 0; jt < 4; ++jt) {
      #pragma unroll
      for (int reg = 0; reg < 16; ++reg) {
        int cl = (reg & 3) + 8 * (reg >> 2) + 4 * kh;
        ep[cl * 36 + l31] = O32[ct][jt][reg];
      }
      asm volatile("s_waitcnt lgkmcnt(0)" ::: "memory");
      __builtin_amdgcn_sched_barrier(0);
      #pragma unroll
      for (int h = 0; h < 4; ++h) {
        const int row = rd_row + 8 * h;
        f32x4 o4 = *reinterpret_cast<const f32x4*>(&ep[row * 36 + rd_ch * 4]);
        const int jg = jt * 32 + rd_ch * 4;
        f32x4 li = *reinterpret_cast<const f32x4*>(&linv_lds[jg]);
        const int c_glob = c0 + ct * 32 + row;
        const float* vr = v + ((size_t)(b * Cc + c_glob)) * Tc + j0 + jg;
        float* orow = out + ((size_t)(b * Cc + c_glob)) * Tc + j0 + jg;
        f32x4 v4 = *reinterpret_cast<const f32x4*>(vr);
        f32x4 o;
        o[0] = v4[0] + li[0] * o4[0];
        o[1] = v4[1] + li[1] * o4[1];
        o[2] = v4[2] + li[2] * o4[2];
        o[3] = v4[3] + li[3] * o4[3];
        *reinterpret_cast<f32x4*>(orow) = o;
      }
      asm volatile("s_waitcnt lgkmcnt(0)" ::: "memory");
      __builtin_amdgcn_sched_barrier(0);
    }
  }
}

extern "C" void kernel_launch(void* const* d_in, const int* in_sizes, int n_in,
                              void* d_out, int out_size, void* d_ws, size_t ws_size,
                              hipStream_t stream) {
  const float* v  = (const float*)d_in[0];
  const float* Wk = (const float*)d_in[1];
  const float* bk = (const float*)d_in[2];
  const float* Wq = (const float*)d_in[3];
  const float* bq = (const float*)d_in[4];
  const float* gm = (const float*)d_in[5];
  float* out = (float*)d_out;

  char* ws = (char*)d_ws;
  u16*   kqb = (u16*)ws;                                   //  8,388,608 B
  u16*   vbf = (u16*)(ws + 8388608);                       // 33,554,432 B
  u16*   Wbf = (u16*)(ws + 8388608 + 33554432);            //    131,072 B
  float* bkq = (float*)(ws + 8388608 + 33554432 + 131072); //        512 B

  prep_kernel<<<dim3(64), dim3(256), 0, stream>>>(Wk, Wq, bk, bq, Wbf, bkq);
  kqv_kernel<<<dim3(Tc / 64, Bc), dim3(256), 0, stream>>>(v, Wbf, bkq, kqb, vbf);
  attn_kernel<<<dim3((Tc / QT) * Bc), dim3(512), 0, stream>>>(v, vbf, kqb, gm, out);
}

// Round 19
// 157.125 us; speedup vs baseline: 2.7763x; 1.0006x over previous
//
#include <hip/hip_runtime.h>

#define Bc 16
#define Cc 512
#define Tc 2048
#define QT 128
#define KT 128
#define NT 16     // Tc / KT
#define LTS 66    // kqv LDS transposed-tile row stride (ushort), 64+2 pad

typedef __attribute__((ext_vector_type(8)))  short short8;
typedef __attribute__((ext_vector_type(4)))  float f32x4;
typedef __attribute__((ext_vector_type(16))) float f32x16;
typedef unsigned short u16;

static __device__ __forceinline__ u16 f2bf(float x) {
  unsigned u = __float_as_uint(x);
  u += 0x7FFF + ((u >> 16) & 1);   // RNE
  return (u16)(u >> 16);
}

// Pack 2 f32 -> 2 bf16 in one VALU op (no builtin on gfx950).
static __device__ __forceinline__ unsigned cvt_pk_bf16(float lo, float hi) {
  unsigned r;
  asm("v_cvt_pk_bf16_f32 %0, %1, %2" : "=v"(r) : "v"(lo), "v"(hi));
  return r;
}

// Async global->LDS, 16B per lane: LDS dest = wave-uniform base + lane*16.
static __device__ __forceinline__ void gload_lds16(const u16* gsrc, u16* ldst) {
  __builtin_amdgcn_global_load_lds(
      (const __attribute__((address_space(1))) unsigned int*)gsrc,
      (__attribute__((address_space(3))) unsigned int*)ldst,
      16, 0, 0);
}

// Barrier that waits ONLY on LDS ops (used in kqv).
static __device__ __forceinline__ void block_sync_lds() {
  __builtin_amdgcn_sched_barrier(0);
  asm volatile("s_waitcnt lgkmcnt(0)" ::: "memory");
  __builtin_amdgcn_s_barrier();
  __builtin_amdgcn_sched_barrier(0);
}

// T4 counted barrier: drain all VMEM older than the newest 4 (next-iter vfA
// prefetch). FIFO semantics force the K-stage complete; vfA stays in flight.
static __device__ __forceinline__ void block_sync_vm4() {
  __builtin_amdgcn_sched_barrier(0);
  asm volatile("s_waitcnt vmcnt(4) lgkmcnt(0)" ::: "memory");
  __builtin_amdgcn_s_barrier();
  __builtin_amdgcn_sched_barrier(0);
}

// ---------------- Kernel 0: W -> bf16 (fused k||q), bias -> bkq ----------------
__global__ __launch_bounds__(256) void prep_kernel(
    const float* __restrict__ Wk, const float* __restrict__ Wq,
    const float* __restrict__ bk, const float* __restrict__ bq,
    u16* __restrict__ Wbf, float* __restrict__ bkq)
{
  int idx  = blockIdx.x * 256 + threadIdx.x;
  int base = idx * 4;
  if (base < 128 * Cc) {
    int ch = base >> 9;
    int c  = base & (Cc - 1);
    const float* src = (ch < 64) ? (Wk + (size_t)ch * Cc + c)
                                 : (Wq + (size_t)(ch - 64) * Cc + c);
    f32x4 w = *reinterpret_cast<const f32x4*>(src);
    uint2 o;
    o.x = (unsigned)f2bf(w[0]) | ((unsigned)f2bf(w[1]) << 16);
    o.y = (unsigned)f2bf(w[2]) | ((unsigned)f2bf(w[3]) << 16);
    *reinterpret_cast<uint2*>(Wbf + base) = o;
  }
  if (idx < 128) bkq[idx] = (idx < 64) ? bk[idx] : bq[idx - 64];
}

// ---------------- Kernel 1: kq[t][ch] via MFMA + vbf16 emission ----------------
__global__ __launch_bounds__(256) void kqv_kernel(
    const float* __restrict__ v, const u16* __restrict__ Wbf,
    const float* __restrict__ bkq, u16* __restrict__ kq, u16* __restrict__ vbf)
{
  __shared__ u16 LDSt[2][64][LTS];
  const int b   = blockIdx.y;
  const int t0  = blockIdx.x * 64;
  const int tid = threadIdx.x;
  const int lane = tid & 63;
  const int w    = tid >> 6;
  const int l15  = lane & 15;
  const int lg   = lane >> 4;

  f32x4 acc[8];
  #pragma unroll
  for (int mt = 0; mt < 8; ++mt) acc[mt] = f32x4{0.f, 0.f, 0.f, 0.f};

  const float* vb = v + (size_t)b * Cc * Tc + t0;
  float x[16];
  #pragma unroll
  for (int r = 0; r < 16; ++r) x[r] = vb[(size_t)(w * 16 + r) * Tc + lane];

  int buf = 0;
  for (int c0 = 0; c0 < Cc; c0 += 64, buf ^= 1) {
    #pragma unroll
    for (int r = 0; r < 16; ++r) {
      u16 hb = f2bf(x[r]);
      LDSt[buf][lane][w * 16 + r] = hb;
      vbf[((size_t)b * Cc + c0 + w * 16 + r) * Tc + t0 + lane] = hb;
    }
    block_sync_lds();
    if (c0 + 64 < Cc) {
      #pragma unroll
      for (int r = 0; r < 16; ++r)
        x[r] = vb[(size_t)(c0 + 64 + w * 16 + r) * Tc + lane];
    }
    #pragma unroll
    for (int ks = 0; ks < 2; ++ks) {
      short8 bfrag = *reinterpret_cast<const short8*>(&LDSt[buf][w * 16 + l15][ks * 32 + lg * 8]);
      #pragma unroll
      for (int mt = 0; mt < 8; ++mt) {
        short8 afrag = *reinterpret_cast<const short8*>(
            Wbf + (size_t)(mt * 16 + l15) * Cc + c0 + ks * 32 + lg * 8);
        acc[mt] = __builtin_amdgcn_mfma_f32_16x16x32_bf16(afrag, bfrag, acc[mt], 0, 0, 0);
      }
    }
  }
  const int t = t0 + w * 16 + l15;
  u16* op = kq + ((size_t)b * Tc + t) * 128;
  #pragma unroll
  for (int mt = 0; mt < 8; ++mt) {
    int chb = mt * 16 + lg * 4;
    uint2 o;
    o.x = cvt_pk_bf16(acc[mt][0] + bkq[chb + 0], acc[mt][1] + bkq[chb + 1]);
    o.y = cvt_pk_bf16(acc[mt][2] + bkq[chb + 2], acc[mt][3] + bkq[chb + 3]);
    *reinterpret_cast<uint2*>(op + chb) = o;
  }
}

// V A-frag loads (2 ks-steps into VF[2][2])
#define VLOAD(VF, KSB, IB)                                                \
  _Pragma("unroll")                                                       \
  for (int ct_ = 0; ct_ < 2; ++ct_)                                       \
    _Pragma("unroll")                                                     \
    for (int kk_ = 0; kk_ < 2; ++kk_)                                     \
      VF[ct_][kk_] = *reinterpret_cast<const short8*>(                    \
          vbase + (size_t)(ct_ * 32 + l31) * Tc + (IB) + ((KSB) + kk_) * 16 + kh * 8);

// PV: 2 ks-steps, 16 MFMA, P read with row&15 XOR (2-way, free)
#define PVSTEP(VF, KSB)                                                   \
  {                                                                       \
    _Pragma("unroll")                                                     \
    for (int kk_ = 0; kk_ < 2; ++kk_) {                                   \
      short8 pf_[4];                                                      \
      _Pragma("unroll")                                                   \
      for (int jt_ = 0; jt_ < 4; ++jt_) {                                 \
        int row_ = jt_ * 32 + l31;                                        \
        int chk_ = ((((KSB) + kk_) * 2 + kh) ^ (row_ & 15)) * 8;          \
        pf_[jt_] = *reinterpret_cast<const short8*>(&P[pb][row_ * 128 + chk_]); \
      }                                                                   \
      _Pragma("unroll")                                                   \
      for (int jt_ = 0; jt_ < 4; ++jt_) {                                 \
        O32[0][jt_] = __builtin_amdgcn_mfma_f32_32x32x16_bf16(VF[0][kk_], pf_[jt_], O32[0][jt_], 0, 0, 0); \
        O32[1][jt_] = __builtin_amdgcn_mfma_f32_32x32x16_bf16(VF[1][kk_], pf_[jt_], O32[1][jt_], 0, 0, 0); \
      }                                                                   \
    }                                                                     \
  }

// ---------------- Kernel 2: KT=128, K via global_load_lds, counted vmcnt ----------------
__global__ __launch_bounds__(512, 2) void attn_kernel(
    const float* __restrict__ v, const u16* __restrict__ vbf,
    const u16* __restrict__ kq, const float* __restrict__ gamma_p,
    float* __restrict__ out)
{
  __shared__ u16 P[2][128 * 128];       // 64 KB; rows 256B, chunk XOR row&15
  __shared__ u16 Klds[2][128 * 64];     // 32 KB; rows 128B, chunk XOR row&7
  __shared__ float lsum_lds[QT];
  __shared__ __align__(16) float linv_lds[QT];
  // epilogue transpose aliases P (done after loop + full syncs)

  // XCD-aware swizzle: 256 blocks, 8 XCDs -> each XCD sees 2 consecutive b's
  const int L   = blockIdx.x;
  const int lin = (L & 7) * 32 + (L >> 3);
  const int b   = lin >> 4;
  const int j0  = (lin & 15) * QT;
  const int tid = threadIdx.x;
  const int lane = tid & 63;
  const int wid  = tid >> 6;      // 0..7 = owned j-tile (S) AND 64-channel slice (PV)
  const int l15  = lane & 15;
  const int lg   = lane >> 4;     // 0..3
  const int l31  = lane & 31;
  const int kh   = lane >> 5;     // 0..1
  const int c0   = wid * 64;

  // K staging: wave stages rows wid*16..wid*16+15 (2 calls of 8 rows each).
  const int sc = (lane & 7) ^ ((lane >> 3) & 7);        // pre-swizzled 16B chunk
  const u16* kqb2 = kq + (size_t)b * Tc * 128;
  u16* kst = &Klds[0][0] + wid * 16 * 64;               // + buf*8192 at use

  // Q B-fragments for S (16x16): n=j=l15, k=d=lg*8+e
  short8 qf0, qf1;
  {
    const u16* qp = kq + (size_t)(b * Tc + j0 + wid * 16 + l15) * 128 + 64 + lg * 8;
    qf0 = *reinterpret_cast<const short8*>(qp);
    qf1 = *reinterpret_cast<const short8*>(qp + 32);
  }

  f32x16 O32[2][4];   // [ct][jt] -> 128 AGPR
  #pragma unroll
  for (int a = 0; a < 2; ++a)
    #pragma unroll
    for (int bb = 0; bb < 4; ++bb)
      #pragma unroll
      for (int e = 0; e < 16; ++e) O32[a][bb][e] = 0.f;

  float lsum = 0.f;

  const u16* vbase = vbf + ((size_t)b * Cc + c0) * Tc;
  short8 vfA[2][2], vfB[2][2];

  // ---- prologue: stage K(0); S(0)->P[0]; stage K(1); prefetch vfA ----
  gload_lds16(kqb2 + (size_t)(wid * 16 + (lane >> 3)) * 128 + sc * 8, kst);
  gload_lds16(kqb2 + (size_t)(wid * 16 + 8 + (lane >> 3)) * 128 + sc * 8, kst + 8 * 64);
  __syncthreads();
  {
    u16* prow = &P[0][(wid * 16 + l15) * 128];
    #pragma unroll
    for (int hg = 0; hg < 2; ++hg) {
      short8 kf[4][2];
      #pragma unroll
      for (int it2 = 0; it2 < 4; ++it2)
        #pragma unroll
        for (int ks = 0; ks < 2; ++ks)
          kf[it2][ks] = *reinterpret_cast<const short8*>(
              &Klds[0][((hg * 4 + it2) * 16 + l15) * 64 + (((ks * 4 + lg) ^ (l15 & 7)) * 8)]);
      f32x4 sacc[4];
      #pragma unroll
      for (int it2 = 0; it2 < 4; ++it2) {
        f32x4 s = f32x4{0.f, 0.f, 0.f, 0.f};
        s = __builtin_amdgcn_mfma_f32_16x16x32_bf16(kf[it2][0], qf0, s, 0, 0, 0);
        s = __builtin_amdgcn_mfma_f32_16x16x32_bf16(kf[it2][1], qf1, s, 0, 0, 0);
        sacc[it2] = s;
      }
      #pragma unroll
      for (int it2 = 0; it2 < 4; ++it2) {
        float p0 = __expf(sacc[it2][0]);
        float p1 = __expf(sacc[it2][1]);
        float p2 = __expf(sacc[it2][2]);
        float p3 = __expf(sacc[it2][3]);
        lsum += (p0 + p1) + (p2 + p3);
        uint2 wv;
        wv.x = cvt_pk_bf16(p0, p1);
        wv.y = cvt_pk_bf16(p2, p3);
        int chk = ((hg * 8 + it2 * 2 + (lg >> 1)) ^ (l15 & 15)) * 8 + (lg & 1) * 4;
        *reinterpret_cast<uint2*>(prow + chk) = wv;
      }
    }
  }
  gload_lds16(kqb2 + (size_t)(KT + wid * 16 + (lane >> 3)) * 128 + sc * 8, kst + 8192);
  gload_lds16(kqb2 + (size_t)(KT + wid * 16 + 8 + (lane >> 3)) * 128 + sc * 8, kst + 8192 + 8 * 64);
  VLOAD(vfA, 0, 0);
  block_sync_vm4();   // K(1) drained (older than vfA), vfA stays in flight

  int pb = 0;
  for (int i = 0; i < NT; ++i, pb ^= 1) {
    const int i0 = i * KT;
    const bool last = (i + 1 >= NT);

    // ---- V ks 2..3 for tile i (oldest VMEM after barrier) ----
    VLOAD(vfB, 2, i0);

    // ---- stage K(i+2) -> Klds[i&1] ----
    if (i + 2 < NT) {
      const size_t kb = (size_t)(i0 + 2 * KT);
      gload_lds16(kqb2 + (kb + wid * 16 + (lane >> 3)) * 128 + sc * 8,
                  kst + (i & 1) * 8192);
      gload_lds16(kqb2 + (kb + wid * 16 + 8 + (lane >> 3)) * 128 + sc * 8,
                  kst + (i & 1) * 8192 + 8 * 64);
    }

    // ---- S(i+1) from Klds[(i+1)&1] + exp + publish P[pb^1], two halves ----
    if (!last) {
      const u16* kl = &Klds[(i + 1) & 1][0];
      u16* prow = &P[pb ^ 1][(wid * 16 + l15) * 128];
      #pragma unroll
      for (int hg = 0; hg < 2; ++hg) {
        short8 kf[4][2];
        #pragma unroll
        for (int it2 = 0; it2 < 4; ++it2)
          #pragma unroll
          for (int ks = 0; ks < 2; ++ks)
            kf[it2][ks] = *reinterpret_cast<const short8*>(
                &kl[((hg * 4 + it2) * 16 + l15) * 64 + (((ks * 4 + lg) ^ (l15 & 7)) * 8)]);
        f32x4 sacc[4];
        #pragma unroll
        for (int it2 = 0; it2 < 4; ++it2) {
          f32x4 s = f32x4{0.f, 0.f, 0.f, 0.f};
          s = __builtin_amdgcn_mfma_f32_16x16x32_bf16(kf[it2][0], qf0, s, 0, 0, 0);
          s = __builtin_amdgcn_mfma_f32_16x16x32_bf16(kf[it2][1], qf1, s, 0, 0, 0);
          sacc[it2] = s;
        }
        #pragma unroll
        for (int it2 = 0; it2 < 4; ++it2) {
          float p0 = __expf(sacc[it2][0]);
          float p1 = __expf(sacc[it2][1]);
          float p2 = __expf(sacc[it2][2]);
          float p3 = __expf(sacc[it2][3]);
          lsum += (p0 + p1) + (p2 + p3);
          uint2 wv;
          wv.x = cvt_pk_bf16(p0, p1);
          wv.y = cvt_pk_bf16(p2, p3);
          int chk = ((hg * 8 + it2 * 2 + (lg >> 1)) ^ (l15 & 15)) * 8 + (lg & 1) * 4;
          *reinterpret_cast<uint2*>(prow + chk) = wv;
        }
      }
    }

    // ---- PV(i): 8 ks-steps, V ping-pong vfA/vfB ----
    PVSTEP(vfA, 0);
    VLOAD(vfA, 4, i0);
    PVSTEP(vfB, 2);
    VLOAD(vfB, 6, i0);
    PVSTEP(vfA, 4);
    if (!last) VLOAD(vfA, 0, i0 + KT);   // next-iter prefetch (newest 4)
    PVSTEP(vfB, 6);

    if (!last) block_sync_vm4();   // K(i+2) drained, vfA(i+1) outstanding
  }

  // ---- denominators ----
  lsum += __shfl_xor(lsum, 16);
  lsum += __shfl_xor(lsum, 32);
  if (lane < 16) lsum_lds[wid * 16 + lane] = lsum;
  __syncthreads();
  const float gamma = *gamma_p;
  if (tid < QT) linv_lds[tid] = gamma / lsum_lds[tid];
  __syncthreads();

  // ---- epilogue: per-wave LDS transpose (aliases P), float4 I/O ----
  float* ep = reinterpret_cast<float*>(&P[0][0]) + wid * (32 * 36);
  const int rd_row = lane >> 3;   // 0..7 (+8h)
  const int rd_ch  = lane & 7;    // j quad
  #pragma unroll
  for (int ct = 0; ct < 2; ++ct) {
    #pragma unroll
    for (int jt = 0; jt < 4; ++jt) {
      #pragma unroll
      for (int reg = 0; reg < 16; ++reg) {
        int cl = (reg & 3) + 8 * (reg >> 2) + 4 * kh;
        ep[cl * 36 + l31] = O32[ct][jt][reg];
      }
      asm volatile("s_waitcnt lgkmcnt(0)" ::: "memory");
      __builtin_amdgcn_sched_barrier(0);
      #pragma unroll
      for (int h = 0; h < 4; ++h) {
        const int row = rd_row + 8 * h;
        f32x4 o4 = *reinterpret_cast<const f32x4*>(&ep[row * 36 + rd_ch * 4]);
        const int jg = jt * 32 + rd_ch * 4;
        f32x4 li = *reinterpret_cast<const f32x4*>(&linv_lds[jg]);
        const int c_glob = c0 + ct * 32 + row;
        const float* vr = v + ((size_t)(b * Cc + c_glob)) * Tc + j0 + jg;
        float* orow = out + ((size_t)(b * Cc + c_glob)) * Tc + j0 + jg;
        f32x4 v4 = *reinterpret_cast<const f32x4*>(vr);
        f32x4 o;
        o[0] = v4[0] + li[0] * o4[0];
        o[1] = v4[1] + li[1] * o4[1];
        o[2] = v4[2] + li[2] * o4[2];
        o[3] = v4[3] + li[3] * o4[3];
        *reinterpret_cast<f32x4*>(orow) = o;
      }
      asm volatile("s_waitcnt lgkmcnt(0)" ::: "memory");
      __builtin_amdgcn_sched_barrier(0);
    }
  }
}

extern "C" void kernel_launch(void* const* d_in, const int* in_sizes, int n_in,
                              void* d_out, int out_size, void* d_ws, size_t ws_size,
                              hipStream_t stream) {
  const float* v  = (const float*)d_in[0];
  const float* Wk = (const float*)d_in[1];
  const float* bk = (const float*)d_in[2];
  const float* Wq = (const float*)d_in[3];
  const float* bq = (const float*)d_in[4];
  const float* gm = (const float*)d_in[5];
  float* out = (float*)d_out;

  char* ws = (char*)d_ws;
  u16*   kqb = (u16*)ws;                                   //  8,388,608 B
  u16*   vbf = (u16*)(ws + 8388608);                       // 33,554,432 B
  u16*   Wbf = (u16*)(ws + 8388608 + 33554432);            //    131,072 B
  float* bkq = (float*)(ws + 8388608 + 33554432 + 131072); //        512 B

  prep_kernel<<<dim3(64), dim3(256), 0, stream>>>(Wk, Wq, bk, bq, Wbf, bkq);
  kqv_kernel<<<dim3(Tc / 64, Bc), dim3(256), 0, stream>>>(v, Wbf, bkq, kqb, vbf);
  attn_kernel<<<dim3((Tc / QT) * Bc), dim3(512), 0, stream>>>(v, vbf, kqb, gm, out);
}